// Round 1
// baseline (329.007 us; speedup 1.0000x reference)
//
#include <hip/hip_runtime.h>

#define BATCH 32768
#define NPHI 35

// ---------- compile-time combinatorics ----------
constexpr int choose2(int n){ return (n*(n-1))/2; }

// lexicographic index of sorted triple (a<b<c) among combinations(7,3)
constexpr int tri_id_sorted(int a,int b,int c){
  int id=0;
  for(int x=0;x<a;++x) id += choose2(6-x);
  for(int y=a+1;y<b;++y) id += (6-y);
  id += (c-b-1);
  return id;
}

constexpr int tri_id3(int a,int b,int c){
  int x=a,y=b,z=c;
  if (x>y){int t=x;x=y;y=t;}
  if (y>z){int t=y;y=z;z=t;}
  if (x>y){int t=x;x=y;y=t;}
  return tri_id_sorted(x,y,z);
}

// parity sign of (a,b,c) w.r.t. sorted order (values distinct)
constexpr int sgn3(int a,int b,int c){
  int inv = (a>b)+(a>c)+(b>c);
  return (inv&1)? -1 : 1;
}

// upper-triangle index for 7x7 symmetric, i<=j
constexpr int UT(int i,int j){
  return i*7 - (i*(i-1))/2 + (j-i);
}

struct Tables {
  int n;
  signed char ut[2944];
  signed char t [2944];
  signed char a [2944];
  signed char b [2944];
  signed char s [2944];
};

constexpr Tables build_tables(){
  Tables tb{};
  tb.n = 0;
  for (int k=0;k<7;++k) for (int l=k+1;l<7;++l)
  for (int m=0;m<7;++m) for (int n2=m+1;n2<7;++n2) {
    if (m==k||m==l||n2==k||n2==l) continue;
    int comp[3]={0,0,0}; int cn=0;
    for (int x=0;x<7;++x) if (x!=k&&x!=l&&x!=m&&x!=n2){ comp[cn]=x; ++cn; }
    int perm[7]={k,l,m,n2,comp[0],comp[1],comp[2]};
    int inv=0;
    for (int i=0;i<7;++i) for (int j=i+1;j<7;++j) if (perm[i]>perm[j]) ++inv;
    const int es = (inv&1)? -1 : 1;
    const int tt = tri_id_sorted(comp[0],comp[1],comp[2]);
    for (int i=0;i<7;++i){ if(i==k||i==l) continue;
      for (int j=i;j<7;++j){ if(j==m||j==n2) continue;
        const int sg = es * sgn3(i,k,l) * sgn3(j,m,n2);
        tb.ut[tb.n] = (signed char)UT(i,j);
        tb.t [tb.n] = (signed char)tt;
        tb.a [tb.n] = (signed char)tri_id3(i,k,l);
        tb.b [tb.n] = (signed char)tri_id3(j,m,n2);
        tb.s [tb.n] = (signed char)sg;
        ++tb.n;
      }
    }
  }
  return tb;
}

static constexpr Tables TB = build_tables();
static_assert(TB.n <= 2944, "table overflow");
constexpr int NT = TB.n;   // expected 2940

// ---------- kernel ----------
__global__ __launch_bounds__(64,1)
void PositivityConstraint_89086211654295_kernel(const float* __restrict__ phi,
                                                float* __restrict__ out){
  const int gid = blockIdx.x*64 + threadIdx.x;   // BATCH == 512*64 exactly

  const float* __restrict__ p = phi + (size_t)gid * NPHI;
  float ph[NPHI];
  #pragma unroll
  for (int i=0;i<NPHI;++i) ph[i] = p[i];

  // B (upper triangle) as cubic polynomial in phi — fully unrolled,
  // all indices compile-time constants -> registers only.
  float U[28];
  #pragma unroll
  for (int i=0;i<28;++i) U[i]=0.f;

  #pragma unroll
  for (int q=0;q<NT;++q){
    const float prod = ph[(int)TB.a[q]] * ph[(int)TB.b[q]];
    const float w = (TB.s[q] > 0) ? ph[(int)TB.t[q]] : -ph[(int)TB.t[q]];
    U[(int)TB.ut[q]] = fmaf(w, prod, U[(int)TB.ut[q]]);
  }

  float A[28];
  #pragma unroll
  for (int i=0;i<28;++i) A[i] = U[i]*(1.0f/6.0f);

  // cyclic Jacobi eigenvalue iteration, 6 sweeps, constant indices
  for (int sweep=0; sweep<6; ++sweep){
    #pragma unroll
    for (int p1=0;p1<7;++p1){
      #pragma unroll
      for (int q1=p1+1;q1<7;++q1){
        const float apq = A[UT(p1,q1)];
        const float app = A[UT(p1,p1)];
        const float aqq = A[UT(q1,q1)];
        float d = 2.0f*apq;
        d = d + ((d >= 0.0f)? 1e-30f : -1e-30f);     // avoid 0/0
        const float tau = (aqq - app)/d;
        float t = 1.0f/(fabsf(tau) + sqrtf(fmaf(tau,tau,1.0f)));
        t = (tau >= 0.0f)? t : -t;
        const float c = 1.0f/sqrtf(fmaf(t,t,1.0f));
        const float s = t*c;
        A[UT(p1,p1)] = fmaf(-t, apq, app);
        A[UT(q1,q1)] = fmaf( t, apq, aqq);
        A[UT(p1,q1)] = 0.0f;
        #pragma unroll
        for (int r=0;r<7;++r){
          if (r==p1 || r==q1) continue;
          const int irp = (r<p1)? UT(r,p1) : UT(p1,r);
          const int irq = (r<q1)? UT(r,q1) : UT(q1,r);
          const float arp = A[irp], arq = A[irq];
          A[irp] = fmaf(c, arp, -s*arq);
          A[irq] = fmaf(s, arp,  c*arq);
        }
      }
    }
  }

  // det(B) = product of eigenvalues; eig(g) = eig(B) / (|det|+1e-12)^(1/9)
  float det = 1.0f;
  #pragma unroll
  for (int i=0;i<7;++i) det *= A[UT(i,i)];
  const float ad = fabsf(det) + 1e-12f;
  const float scale = exp2f(log2f(ad) * (1.0f/9.0f));
  const float inv = 1.0f/scale;

  float sum = 0.0f;
  #pragma unroll
  for (int i=0;i<7;++i){
    const float ev = A[UT(i,i)]*inv;
    const float r = 1e-6f - ev;
    sum += fmaxf(r, 0.0f);
  }
  out[gid] = sum;
}

// ---------- launch ----------
extern "C" void kernel_launch(void* const* d_in, const int* in_sizes, int n_in,
                              void* d_out, int out_size, void* d_ws, size_t ws_size,
                              hipStream_t stream) {
  const float* phi = (const float*)d_in[0];
  float* out = (float*)d_out;
  (void)in_sizes; (void)n_in; (void)out_size; (void)d_ws; (void)ws_size;
  hipLaunchKernelGGL(PositivityConstraint_89086211654295_kernel,
                     dim3(BATCH/64), dim3(64), 0, stream, phi, out);
}

// Round 2
// 65.081 us; speedup vs baseline: 5.0554x; 5.0554x over previous
//
#include <hip/hip_runtime.h>
#include <utility>

#define BATCH 32768
#define NPHI 35

// ---------- compile-time combinatorics ----------
constexpr int choose2(int n){ return (n*(n-1))/2; }

// lexicographic index of sorted triple (a<b<c) among combinations(7,3)
constexpr int tri_id_sorted(int a,int b,int c){
  int id=0;
  for(int x=0;x<a;++x) id += choose2(6-x);
  for(int y=a+1;y<b;++y) id += (6-y);
  id += (c-b-1);
  return id;
}

constexpr int tri_id3(int a,int b,int c){
  int x=a,y=b,z=c;
  if (x>y){int t=x;x=y;y=t;}
  if (y>z){int t=y;y=z;z=t;}
  if (x>y){int t=x;x=y;y=t;}
  return tri_id_sorted(x,y,z);
}

// parity sign of (a,b,c) w.r.t. sorted order (values distinct)
constexpr int sgn3(int a,int b,int c){
  int inv = (a>b)+(a>c)+(b>c);
  return (inv&1)? -1 : 1;
}

// upper-triangle index for 7x7 symmetric, i<=j
constexpr int UT(int i,int j){
  return i*7 - (i*(i-1))/2 + (j-i);
}

// pair index for k<l among C(7,2)=21
constexpr int PAIR(int k,int l){
  return k*7 - (k*(k+1))/2 + (l - k - 1);
}

// ---------- the straight-line "program": 1470 fma-like ops ----------
// kind 0: T[dst] (+)= s*ph[a]*ph[b]      (T = per-(k,l) contraction C·pf)
// kind 1: U[dst] (+)= s*ph[a]*T[b]       (B upper triangle accumulation)
// Interleaved per (k,l) group so T liveness stays ~7 values.
struct Prog {
  int n;
  unsigned char kind[1472];
  unsigned char init[1472];   // 1 = first write to dst (use mul, not fma)
  short         dst [1472];
  unsigned char a   [1472];
  short         b   [1472];
  signed char   s   [1472];
};

constexpr Prog build_prog(){
  Prog P{}; P.n=0;
  bool uinit[28]={};
  for(int k=0;k<7;++k) for(int l=k+1;l<7;++l){
    const int kl = PAIR(k,l);
    bool tinit[7]={};
    // ---- T phase for this (k,l): T_{kl,j} = sum_{m<n} eps_hat * pf_{jmn} * phi_comp
    for(int m=0;m<7;++m) for(int n2=m+1;n2<7;++n2){
      if(m==k||m==l||n2==k||n2==l) continue;
      int comp[3]={0,0,0}; int cn=0;
      for(int x=0;x<7;++x) if(x!=k&&x!=l&&x!=m&&x!=n2){ comp[cn]=x; ++cn; }
      int perm[7]={k,l,m,n2,comp[0],comp[1],comp[2]};
      int invc=0;
      for(int i=0;i<7;++i) for(int j=i+1;j<7;++j) if(perm[i]>perm[j]) ++invc;
      const int es=(invc&1)? -1 : 1;
      const int tcomp=tri_id_sorted(comp[0],comp[1],comp[2]);
      for(int j=0;j<7;++j){
        if(j==m||j==n2) continue;
        P.kind[P.n]=0;
        P.init[P.n]=tinit[j]?0:1; tinit[j]=true;
        P.dst [P.n]=(short)(kl*7+j);
        P.a   [P.n]=(unsigned char)tcomp;
        P.b   [P.n]=(short)tri_id3(j,m,n2);
        P.s   [P.n]=(signed char)(es*sgn3(j,m,n2));
        ++P.n;
      }
    }
    // ---- B phase for this (k,l): U[i<=j] += sgn3(i,k,l)*phi_{ikl}*T_{kl,j}
    for(int i=0;i<7;++i){
      if(i==k||i==l) continue;
      for(int j=i;j<7;++j){
        P.kind[P.n]=1;
        P.init[P.n]=uinit[UT(i,j)]?0:1; uinit[UT(i,j)]=true;
        P.dst [P.n]=(short)UT(i,j);
        P.a   [P.n]=(unsigned char)tri_id3(i,k,l);
        P.b   [P.n]=(short)(kl*7+j);
        P.s   [P.n]=(signed char)sgn3(i,k,l);
        ++P.n;
      }
    }
  }
  return P;
}

static constexpr Prog PROG = build_prog();
static_assert(PROG.n == 1470, "program size unexpected");

// ---------- guaranteed-constant-index execution via fold expression ----------
template<int Q>
__device__ __forceinline__ void step(float (&T)[147], float (&U)[28],
                                     const float (&ph)[NPHI]){
  constexpr int  d = PROG.dst[Q];
  constexpr int  a = PROG.a[Q];
  constexpr int  b = PROG.b[Q];
  constexpr bool neg  = (PROG.s[Q] < 0);
  constexpr bool init = (PROG.init[Q] != 0);
  if constexpr (PROG.kind[Q] == 0){
    const float x = neg ? -ph[a] : ph[a];
    if constexpr (init) T[d] = x * ph[b];
    else                T[d] = fmaf(x, ph[b], T[d]);
  } else {
    const float x = neg ? -ph[a] : ph[a];
    if constexpr (init) U[d] = x * T[b];
    else                U[d] = fmaf(x, T[b], U[d]);
  }
}

template<int... Q>
__device__ __forceinline__ void run_prog(float (&T)[147], float (&U)[28],
                                         const float (&ph)[NPHI],
                                         std::integer_sequence<int, Q...>){
  (step<Q>(T, U, ph), ...);
}

// ---------- kernel ----------
__global__ __launch_bounds__(64,1)
void PositivityConstraint_89086211654295_kernel(const float* __restrict__ phi,
                                                float* __restrict__ out){
  const int gid = blockIdx.x*64 + threadIdx.x;   // BATCH == 512*64 exactly

  const float* __restrict__ p = phi + (size_t)gid * NPHI;
  float ph[NPHI];
  #pragma unroll
  for (int i=0;i<NPHI;++i) ph[i] = p[i];

  float T[147];   // scalarized by constant indexing; short live ranges
  float U[28];
  run_prog(T, U, ph, std::make_integer_sequence<int, PROG.n>{});

  float A[28];
  #pragma unroll
  for (int i=0;i<28;++i) A[i] = U[i]*(1.0f/6.0f);

  // cyclic Jacobi eigenvalue iteration, 6 sweeps, constant indices,
  // approximate HW rcp/rsq/sqrt (1 ulp — far inside tolerance)
  for (int sweep=0; sweep<6; ++sweep){
    #pragma unroll
    for (int p1=0;p1<7;++p1){
      #pragma unroll
      for (int q1=p1+1;q1<7;++q1){
        const float apq = A[UT(p1,q1)];
        const float app = A[UT(p1,p1)];
        const float aqq = A[UT(q1,q1)];
        float d = 2.0f*apq;
        d = d + ((d >= 0.0f)? 1e-30f : -1e-30f);     // avoid 0/0
        const float tau = (aqq - app) * __builtin_amdgcn_rcpf(d);
        float t = __builtin_amdgcn_rcpf(
                    fabsf(tau) + __builtin_amdgcn_sqrtf(fmaf(tau,tau,1.0f)));
        t = (tau >= 0.0f)? t : -t;
        const float c = __builtin_amdgcn_rsqf(fmaf(t,t,1.0f));
        const float s = t*c;
        A[UT(p1,p1)] = fmaf(-t, apq, app);
        A[UT(q1,q1)] = fmaf( t, apq, aqq);
        A[UT(p1,q1)] = 0.0f;
        #pragma unroll
        for (int r=0;r<7;++r){
          if (r==p1 || r==q1) continue;
          const int irp = (r<p1)? UT(r,p1) : UT(p1,r);
          const int irq = (r<q1)? UT(r,q1) : UT(q1,r);
          const float arp = A[irp], arq = A[irq];
          A[irp] = fmaf(c, arp, -s*arq);
          A[irq] = fmaf(s, arp,  c*arq);
        }
      }
    }
  }

  // det(B) = product of eigenvalues; eig(g) = eig(B) / (|det|+1e-12)^(1/9)
  float det = 1.0f;
  #pragma unroll
  for (int i=0;i<7;++i) det *= A[UT(i,i)];
  const float ad = fabsf(det) + 1e-12f;
  const float scale = __builtin_amdgcn_exp2f(__builtin_amdgcn_logf(ad) * (1.0f/9.0f));
  const float inv = __builtin_amdgcn_rcpf(scale);

  float sum = 0.0f;
  #pragma unroll
  for (int i=0;i<7;++i){
    const float ev = A[UT(i,i)]*inv;
    const float r = 1e-6f - ev;
    sum += fmaxf(r, 0.0f);
  }
  out[gid] = sum;
}

// ---------- launch ----------
extern "C" void kernel_launch(void* const* d_in, const int* in_sizes, int n_in,
                              void* d_out, int out_size, void* d_ws, size_t ws_size,
                              hipStream_t stream) {
  const float* phi = (const float*)d_in[0];
  float* out = (float*)d_out;
  (void)in_sizes; (void)n_in; (void)out_size; (void)d_ws; (void)ws_size;
  hipLaunchKernelGGL(PositivityConstraint_89086211654295_kernel,
                     dim3(BATCH/64), dim3(64), 0, stream, phi, out);
}